// Round 4
// baseline (374.168 us; speedup 1.0000x reference)
//
#include <hip/hip_runtime.h>
#include <cstdint>
#include <cstddef>

// Problem constants
#define BATCH  32
#define TSTEPS 1024
#define INDIM  512
#define HIDDIM 512
#define MTOT   (BATCH * TSTEPS)   // 32768 GEMM rows

// GEMM tiling: 256-thread block computes 256(m) x 128(n); thread = 16x8
#define GMB 256
#define GNB 128
#define GKC 32
#define GKT (INDIM / GKC)         // 16 k-tiles
#define GNBLK (HIDDIM / GNB)      // 4

// Scan tiling
#define SB_H 256                  // h per block
#define SB_T 64                   // t-steps per chunk
#define SB_NC (TSTEPS / SB_T)     // 16 chunks

constexpr float ALPHA = 0.951229424500714f;  // exp(-1/20)

// bijective group swizzle: low3 ^= high bits (keeps within-group order)
__device__ __forceinline__ int swzA(int g) { return g ^ (g >> 3); }   // g in [0,64)
__device__ __forceinline__ int swzB(int g) { return g ^ (g >> 3); }   // g in [0,32)

// ---------------------------------------------------------------------------
// Kernel 1: z[m][n] = sum_k x[m][k] * W[n][k]  (raw; bias added in scan)
// TM=16 x TN=8 per thread -> 0.75 B LDS-read per FMA (was 1.0): LDS pipe off
// the critical path. Single-buffer KC=32, two barriers (proven skeleton).
// Ascending-k fmaf chain per output element -> bit-identical to rounds 1-3.
// ---------------------------------------------------------------------------
__global__ __launch_bounds__(256, 2)
void snn_gemm(const float* __restrict__ x, const float* __restrict__ W,
              float* __restrict__ z)
{
    __shared__ float Asm[GKC][GMB];   // 32 KB, [k][m], f4-group swizzled cols
    __shared__ float Bsm[GKC][GNB];   // 16 KB, [k][n], f4-group swizzled cols

    const int tid = threadIdx.x;
    const int mb  = blockIdx.x / GNBLK;
    const int nb  = blockIdx.x % GNBLK;     // nb fastest: 4 blocks share x-tile
    const int m0  = mb * GMB;
    const int n0  = nb * GNB;

    // ---- staging maps (per-thread full rows; L1 absorbs the 2KB stride)
    // A: thread tid loads x[m0+tid][kt*32 .. +31] = 8 float4
    const float4* Ag = reinterpret_cast<const float4*>(x + (size_t)(m0 + tid) * INDIM);
    const int   acol = (swzA(tid >> 2) << 2) | (tid & 3);      // swizzled col for m=tid
    // B: thread loads W[n0+(tid&127)][kt*32 + (tid>>7)*16 .. +15] = 4 float4
    const int   brow = tid & 127;
    const int   bkq  = (tid >> 7) * 4;                          // f4 offset in k
    const float4* Bg = reinterpret_cast<const float4*>(W + (size_t)(n0 + brow) * INDIM) + bkq;
    const int   bcol = (swzB(brow >> 2) << 2) | (brow & 3);

    // ---- compute map: cm = (tid>>4)*16 (A: 4 bcast addrs/wave), cn = (tid&15)*8
    const int cm = (tid >> 4) * 16;
    const int cn = (tid & 15) * 8;
    int pa[4], pb[2];
#pragma unroll
    for (int i = 0; i < 4; ++i) pa[i] = swzA((cm >> 2) + i);
#pragma unroll
    for (int j = 0; j < 2; ++j) pb[j] = swzB((cn >> 2) + j);

    float acc[16][8];
#pragma unroll
    for (int i = 0; i < 16; ++i)
#pragma unroll
        for (int j = 0; j < 8; ++j) acc[i][j] = 0.0f;

    float4 sa[8], sb[4];
#pragma unroll
    for (int q = 0; q < 8; ++q) sa[q] = Ag[q];
#pragma unroll
    for (int q = 0; q < 4; ++q) sb[q] = Bg[q];

    for (int kt = 0; kt < GKT; ++kt) {
        __syncthreads();   // previous compute done reading LDS
        // ---- stage: transpose regs -> [k][col] LDS (2-way writes = free)
#pragma unroll
        for (int q = 0; q < 8; ++q) {
            const int k4 = q * 4;
            Asm[k4 + 0][acol] = sa[q].x;
            Asm[k4 + 1][acol] = sa[q].y;
            Asm[k4 + 2][acol] = sa[q].z;
            Asm[k4 + 3][acol] = sa[q].w;
        }
#pragma unroll
        for (int q = 0; q < 4; ++q) {
            const int k4 = (bkq + q) * 4;
            Bsm[k4 + 0][bcol] = sb[q].x;
            Bsm[k4 + 1][bcol] = sb[q].y;
            Bsm[k4 + 2][bcol] = sb[q].z;
            Bsm[k4 + 3][bcol] = sb[q].w;
        }
        __syncthreads();

        // issue next tile's global loads; complete during compute
        if (kt + 1 < GKT) {
            Ag += GKC / 4;
            Bg += GKC / 4;
#pragma unroll
            for (int q = 0; q < 8; ++q) sa[q] = Ag[q];
#pragma unroll
            for (int q = 0; q < 4; ++q) sb[q] = Bg[q];
        }

        // ---- compute 32 k-steps from LDS: 6 x ds_read_b128 + 128 fma / kc
#pragma unroll 4
        for (int kc = 0; kc < GKC; ++kc) {
            const float4* Ar = reinterpret_cast<const float4*>(&Asm[kc][0]);
            const float4* Br = reinterpret_cast<const float4*>(&Bsm[kc][0]);
            float4 a0 = Ar[pa[0]];
            float4 a1 = Ar[pa[1]];
            float4 a2 = Ar[pa[2]];
            float4 a3 = Ar[pa[3]];
            float4 b0 = Br[pb[0]];
            float4 b1 = Br[pb[1]];
            const float av[16] = {a0.x, a0.y, a0.z, a0.w, a1.x, a1.y, a1.z, a1.w,
                                  a2.x, a2.y, a2.z, a2.w, a3.x, a3.y, a3.z, a3.w};
            const float bv[8]  = {b0.x, b0.y, b0.z, b0.w, b1.x, b1.y, b1.z, b1.w};
#pragma unroll
            for (int i = 0; i < 16; ++i)
#pragma unroll
                for (int j = 0; j < 8; ++j)
                    acc[i][j] = fmaf(av[i], bv[j], acc[i][j]);
        }
    }

    // ---- epilogue: 16 rows x 2 float4 (16 lanes cover 512B/row: coalesced)
#pragma unroll
    for (int i = 0; i < 16; ++i) {
        float* zr = z + (size_t)(m0 + cm + i) * HIDDIM + n0 + cn;
        float4 v0 = {acc[i][0], acc[i][1], acc[i][2], acc[i][3]};
        float4 v1 = {acc[i][4], acc[i][5], acc[i][6], acc[i][7]};
        *reinterpret_cast<float4*>(zr)     = v0;
        *reinterpret_cast<float4*>(zr + 4) = v1;
    }
}

// ---------------------------------------------------------------------------
// Kernel 2: membrane scan. 64 blocks x 256 thr; chunk = 64 t x 256 h staged
// into LDS via async global_load_lds (wave-uniform LDS base + lane*16B).
// Counted s_waitcnt vmcnt(16) + raw s_barrier keeps next chunk's loads in
// flight across the barrier (__syncthreads would drain vmcnt -> serialize).
// In-place safe (chunk-c stores only touch chunk-c rows).
// ---------------------------------------------------------------------------
__global__ __launch_bounds__(256)
void snn_scan(const float* __restrict__ zsrc, float* __restrict__ out,
              const float* __restrict__ bias, const float* __restrict__ thr)
{
    __shared__ float zl[2][SB_T][SB_H];   // 128 KB

    const int tid  = threadIdx.x;
    const int lane = tid & 63;
    const int wave = tid >> 6;
    const int b    = blockIdx.x >> 1;
    const int h0   = (blockIdx.x & 1) * SB_H;

    const float bb = bias[h0 + tid];
    const float tt = thr[h0 + tid];
    float mem = 0.0f;

    const float* zbase = zsrc + (size_t)b * TSTEPS * HIDDIM + h0;
    float*       obase = out  + (size_t)b * TSTEPS * HIDDIM + h0;

    // issue one chunk: wave w loads rows w*16..w*16+15 (1KB row = 64 lanes x 16B)
    auto issue = [&](int c, int buf) {
        const float* gr = zbase + ((size_t)c * SB_T + wave * 16) * HIDDIM + lane * 4;
        const float* lr = &zl[buf][wave * 16][0];
#pragma unroll
        for (int r = 0; r < 16; ++r) {
            __builtin_amdgcn_global_load_lds(
                (const __attribute__((address_space(1))) void*)gr,
                (__attribute__((address_space(3))) void*)lr, 16, 0, 0);
            gr += HIDDIM;
            lr += SB_H;
        }
    };

    issue(0, 0);

    for (int c = 0; c < SB_NC; ++c) {
        const int buf = c & 1;
        if (c + 1 < SB_NC) {
            issue(c + 1, buf ^ 1);              // prev-prev buffer: free since last barrier
            asm volatile("s_waitcnt vmcnt(16)" ::: "memory");  // chunk c landed; c+1 in flight
        } else {
            asm volatile("s_waitcnt vmcnt(0)" ::: "memory");   // last chunk: full drain
        }
        __builtin_amdgcn_sched_barrier(0);
        __builtin_amdgcn_s_barrier();

        float* orow = obase + (size_t)c * SB_T * HIDDIM + tid;
#pragma unroll 8
        for (int r = 0; r < SB_T; ++r) {
            float zv = zl[buf][r][tid] + bb;
            mem = fmaf(ALPHA, mem, zv);
            bool s = (mem >= tt);
            orow[(size_t)r * HIDDIM] = s ? 1.0f : 0.0f;
            mem = s ? 0.0f : mem;
        }

        asm volatile("s_waitcnt lgkmcnt(0)" ::: "memory");  // LDS reads done before buffer reuse
        __builtin_amdgcn_sched_barrier(0);
        __builtin_amdgcn_s_barrier();
    }

    out[(size_t)MTOT * HIDDIM + (size_t)b * HIDDIM + h0 + tid] = mem;
}

extern "C" void kernel_launch(void* const* d_in, const int* in_sizes, int n_in,
                              void* d_out, int out_size, void* d_ws, size_t ws_size,
                              hipStream_t stream)
{
    const float* x    = (const float*)d_in[0];
    const float* W    = (const float*)d_in[1];
    const float* bias = (const float*)d_in[2];
    const float* thr  = (const float*)d_in[3];
    float* out = (float*)d_out;

    (void)in_sizes; (void)n_in; (void)out_size;

    const size_t z_bytes = (size_t)MTOT * HIDDIM * sizeof(float);  // 64 MB
    float* zbuf = (ws_size >= z_bytes) ? (float*)d_ws : out;       // in-place safe

    dim3 ggrid((MTOT / GMB) * GNBLK);  // 512 blocks
    hipLaunchKernelGGL(snn_gemm, ggrid, dim3(256), 0, stream, x, W, zbuf);

    dim3 sgrid(BATCH * (HIDDIM / SB_H));  // 64 blocks
    hipLaunchKernelGGL(snn_scan, sgrid, dim3(256), 0, stream, zbuf, out, bias, thr);
}

// Round 5
// 349.517 us; speedup vs baseline: 1.0705x; 1.0705x over previous
//
#include <hip/hip_runtime.h>
#include <cstdint>
#include <cstddef>

// Problem constants
#define BATCH  32
#define TSTEPS 1024
#define INDIM  512
#define HIDDIM 512
#define MTOT   (BATCH * TSTEPS)   // 32768 GEMM rows

// GEMM tiling (round-3 proven shape + double-buffered LDS)
#define MB 128
#define NB 128
#define KC 32
#define KT (INDIM / KC)           // 16 k-tiles
#define NBLK (HIDDIM / NB)        // 4

// Scan tiling: 256 blocks x 1 wave, chunk = 64t x 64h
#define SH 64
#define ST 64
#define SNC (TSTEPS / ST)         // 16 chunks

constexpr float ALPHA = 0.951229424500714f;  // exp(-1/20)

__device__ __forceinline__ int swzg(int g) { return g ^ (g >> 3); }  // g in [0,32)

// ---------------------------------------------------------------------------
// Kernel 1: z[m][n] = sum_k x[m][k] * W[n][k]  (raw; bias added in scan)
// 128x128 tile, 8x8 acc/thread (round-3 compute, bit-identical fmaf chain).
// NEW: double-buffered LDS -> ONE barrier per k-tile; the LDS-write of tile
// t+1 and the global loads of t+2 are issued before compute of tile t, so
// the LDS pipe and FMA pipe overlap across waves instead of serializing.
// ---------------------------------------------------------------------------
__global__ __launch_bounds__(256)
void snn_gemm(const float* __restrict__ x, const float* __restrict__ W,
              float* __restrict__ z)
{
    __shared__ float Asm[2][KC][MB];   // 2 x 16 KB
    __shared__ float Bsm[2][KC][NB];   // 2 x 16 KB

    const int tid = threadIdx.x;
    const int mb  = blockIdx.x / NBLK;
    const int nb  = blockIdx.x % NBLK;
    const int m0  = mb * MB;
    const int n0  = nb * NB;

    // staging map: 2 threads per row, 4 consecutive float4 along k each
    const int sr = tid >> 1;           // 0..127
    const int sc = (tid & 1) * 4;      // f4 index 0 or 4
    const int swr = (swzg(sr >> 2) << 2) | (sr & 3);   // swizzled LDS column

    const float4* Ag = reinterpret_cast<const float4*>(x + (size_t)(m0 + sr) * INDIM) + sc;
    const float4* Bg = reinterpret_cast<const float4*>(W + (size_t)(n0 + sr) * INDIM) + sc;

    // compute map: 8x8 sub-tile
    const int cm = (tid >> 4) * 8;
    const int cn = (tid & 15) * 8;
    const int am0 = swzg(cm >> 2), am1 = swzg((cm >> 2) + 1);
    const int bn0 = swzg(cn >> 2), bn1 = swzg((cn >> 2) + 1);

    float acc[8][8];
#pragma unroll
    for (int i = 0; i < 8; ++i)
#pragma unroll
        for (int j = 0; j < 8; ++j) acc[i][j] = 0.0f;

    float4 sa[4], sb[4];

    auto gload = [&]() {
#pragma unroll
        for (int q = 0; q < 4; ++q) { sa[q] = Ag[q]; sb[q] = Bg[q]; }
        Ag += KC / 4;
        Bg += KC / 4;
    };
    auto lwrite = [&](int p) {
#pragma unroll
        for (int q = 0; q < 4; ++q) {
            const int kq = (sc + q) * 4;
            Asm[p][kq + 0][swr] = sa[q].x;
            Asm[p][kq + 1][swr] = sa[q].y;
            Asm[p][kq + 2][swr] = sa[q].z;
            Asm[p][kq + 3][swr] = sa[q].w;
            Bsm[p][kq + 0][swr] = sb[q].x;
            Bsm[p][kq + 1][swr] = sb[q].y;
            Bsm[p][kq + 2][swr] = sb[q].z;
            Bsm[p][kq + 3][swr] = sb[q].w;
        }
    };

    // prologue: tile 0 -> buf0; tile 1 -> regs
    gload();
    lwrite(0);
    __syncthreads();
    gload();                       // tile 1 in regs

    for (int kt = 0; kt < KT; ++kt) {
        const int p = kt & 1;
        if (kt + 1 < KT) lwrite(p ^ 1);     // stage tile kt+1 (other buffer)
        if (kt + 2 < KT) gload();           // issue tile kt+2 loads

        const float (*Ap)[MB] = Asm[p];
        const float (*Bp)[NB] = Bsm[p];
#pragma unroll 8
        for (int kc = 0; kc < KC; ++kc) {
            const float4* Ar = reinterpret_cast<const float4*>(&Ap[kc][0]);
            const float4* Br = reinterpret_cast<const float4*>(&Bp[kc][0]);
            float4 a0 = Ar[am0];
            float4 a1 = Ar[am1];
            float4 b0 = Br[bn0];
            float4 b1 = Br[bn1];
            const float av[8] = {a0.x, a0.y, a0.z, a0.w, a1.x, a1.y, a1.z, a1.w};
            const float bv[8] = {b0.x, b0.y, b0.z, b0.w, b1.x, b1.y, b1.z, b1.w};
#pragma unroll
            for (int i = 0; i < 8; ++i)
#pragma unroll
                for (int j = 0; j < 8; ++j)
                    acc[i][j] = fmaf(av[i], bv[j], acc[i][j]);
        }
        if (kt + 1 < KT) __syncthreads();   // one barrier per tile
    }

    // epilogue: store raw z (rows fully covered: clean 64B lines)
#pragma unroll
    for (int i = 0; i < 8; ++i) {
        float* zr = z + (size_t)(m0 + cm + i) * HIDDIM + n0 + cn;
        float4 v0 = {acc[i][0], acc[i][1], acc[i][2], acc[i][3]};
        float4 v1 = {acc[i][4], acc[i][5], acc[i][6], acc[i][7]};
        *reinterpret_cast<float4*>(zr)     = v0;
        *reinterpret_cast<float4*>(zr + 4) = v1;
    }
}

// ---------------------------------------------------------------------------
// Kernel 2: membrane scan. 256 blocks (one per (b, 64-h tile)) x 1 wave ->
// all 256 CUs active (round-4 used 64 -> per-CU-BW-bound at 108 us).
// Chunk = 64t x 64h (16 KB) double-buffered via global_load_lds; counted
// vmcnt keeps chunk c+1 in flight while computing c. Spikes staged in LDS
// and stored as 16 float4 per chunk so the vmcnt FIFO stays countable.
// Single-wave block: no barriers at all, only waitcnts.
// ---------------------------------------------------------------------------
__global__ __launch_bounds__(64)
void snn_scan(const float* __restrict__ zsrc, float* __restrict__ out,
              const float* __restrict__ bias, const float* __restrict__ thr)
{
    __shared__ float zl[2][ST][SH];    // 2 x 16 KB
    __shared__ float stile[ST][SH];    // 16 KB

    const int lane = threadIdx.x;          // 0..63
    const int b    = blockIdx.x >> 3;
    const int h0   = (blockIdx.x & 7) * SH;

    const float* zbase = zsrc + (size_t)b * TSTEPS * HIDDIM + h0;
    float*       obase = out  + (size_t)b * TSTEPS * HIDDIM + h0;

    const float bb = bias[h0 + lane];
    const float tt = thr[h0 + lane];
    float mem = 0.0f;

    // issue chunk c into buf: 16 x (64 lanes x 16B). Instr j covers t-rows
    // c*64+j*4 .. +3; lane l -> t-row j*4+(l>>4), h (l&15)*4. LDS dest is
    // linear (uniform base + lane*16) and matches that layout exactly.
    auto issue = [&](int c, int buf) {
#pragma unroll
        for (int j = 0; j < 16; ++j) {
            const float* gr = zbase + (size_t)(c * ST + j * 4 + (lane >> 4)) * HIDDIM
                            + (lane & 15) * 4;
            const float* lr = &zl[buf][j * 4][0];
            __builtin_amdgcn_global_load_lds(
                (const __attribute__((address_space(1))) void*)gr,
                (__attribute__((address_space(3))) void*)lr, 16, 0, 0);
        }
    };

    issue(0, 0);

    for (int c = 0; c < SNC; ++c) {
        const int buf = c & 1;
        if (c + 1 < SNC) issue(c + 1, buf ^ 1);

        // FIFO at this point: loads(c) [16] | stores(c-1) [16] | loads(c+1) [16]
        // -> wait for loads(c): allow 32 in steady state, 16 at the edges.
        if (c == 0 || c + 1 >= SNC)
            asm volatile("s_waitcnt vmcnt(16)" ::: "memory");
        else
            asm volatile("s_waitcnt vmcnt(32)" ::: "memory");
        __builtin_amdgcn_sched_barrier(0);

        // 64 serial membrane steps; LDS reads 2-way (free), spike -> stile
#pragma unroll 8
        for (int r = 0; r < ST; ++r) {
            float zv = zl[buf][r][lane] + bb;
            mem = fmaf(ALPHA, mem, zv);
            bool s = (mem >= tt);
            stile[r][lane] = s ? 1.0f : 0.0f;
            mem = s ? 0.0f : mem;
        }

        asm volatile("s_waitcnt lgkmcnt(0)" ::: "memory");   // stile visible (1 wave)
        __builtin_amdgcn_sched_barrier(0);

        // 16 coalesced float4 stores (4 x 256B segments each)
        const float* sf = &stile[0][0];
#pragma unroll
        for (int j = 0; j < 16; ++j) {
            float4 v = *reinterpret_cast<const float4*>(sf + j * 256 + lane * 4);
            float* gp = obase + (size_t)(c * ST + j * 4 + (lane >> 4)) * HIDDIM
                      + (lane & 15) * 4;
            *reinterpret_cast<float4*>(gp) = v;
        }
    }

    out[(size_t)MTOT * HIDDIM + (size_t)b * HIDDIM + h0 + lane] = mem;
}

extern "C" void kernel_launch(void* const* d_in, const int* in_sizes, int n_in,
                              void* d_out, int out_size, void* d_ws, size_t ws_size,
                              hipStream_t stream)
{
    const float* x    = (const float*)d_in[0];
    const float* W    = (const float*)d_in[1];
    const float* bias = (const float*)d_in[2];
    const float* thr  = (const float*)d_in[3];
    float* out = (float*)d_out;

    (void)in_sizes; (void)n_in; (void)out_size;

    const size_t z_bytes = (size_t)MTOT * HIDDIM * sizeof(float);  // 64 MB
    float* zbuf = (ws_size >= z_bytes) ? (float*)d_ws : out;       // in-place safe

    dim3 ggrid((MTOT / MB) * NBLK);  // 1024 blocks
    hipLaunchKernelGGL(snn_gemm, ggrid, dim3(256), 0, stream, x, W, zbuf);

    dim3 sgrid(BATCH * (HIDDIM / SH));  // 256 blocks x 64 threads
    hipLaunchKernelGGL(snn_scan, sgrid, dim3(64), 0, stream, zbuf, out, bias, thr);
}

// Round 7
// 334.841 us; speedup vs baseline: 1.1175x; 1.0438x over previous
//
#include <hip/hip_runtime.h>
#include <cstdint>
#include <cstddef>

// Problem constants
#define BATCH  32
#define TSTEPS 1024
#define INDIM  512
#define HIDDIM 512
#define MTOT   (BATCH * TSTEPS)   // 32768 GEMM rows

// GEMM tiling (round-3 kernel, measured 218 us, absmax 0.0)
#define MB 128
#define NB 128
#define KC 32
#define KTILES (INDIM / KC)       // 16
#define NBLK   (HIDDIM / NB)      // 4

// Scan tiling: 256 blocks x 2 waves (producer/consumer), chunk = 32t x 64h
#define SH 64
#define ST 32
#define SNC (TSTEPS / ST)         // 32 chunks

constexpr float ALPHA = 0.951229424500714f;  // exp(-1/20)

__device__ __forceinline__ int swzg(int g) { return g ^ (g >> 3); }

// ---------------------------------------------------------------------------
// Kernel 1: z[m][n] = sum_k x[m][k] * W[n][k]  (raw; bias added in scan)
// Round-3 kernel verbatim: 128x128 tile, 8x8 acc/thread, KC=32 single-buffer
// LDS, reg-staged next-tile loads. Ascending-k fmaf chain -> bit-exact.
// ---------------------------------------------------------------------------
__global__ __launch_bounds__(256)
void snn_gemm(const float* __restrict__ x, const float* __restrict__ W,
              float* __restrict__ z)
{
    __shared__ float Asm[KC][MB];   // 16 KB
    __shared__ float Bsm[KC][NB];   // 16 KB

    const int tid = threadIdx.x;
    const int mb  = blockIdx.x / NBLK;
    const int nb  = blockIdx.x % NBLK;
    const int m0  = mb * MB;
    const int n0  = nb * NB;

    const int sr = tid >> 1;           // 0..127
    const int sc = (tid & 1) * 4;      // f4 index 0 or 4
    const int srg = sr >> 2;
    const int swr = (swzg(srg) << 2) | (sr & 3);

    const float4* Ag = reinterpret_cast<const float4*>(x + (size_t)(m0 + sr) * INDIM) + sc;
    const float4* Bg = reinterpret_cast<const float4*>(W + (size_t)(n0 + sr) * INDIM) + sc;

    const int cm = (tid >> 4) * 8;
    const int cn = (tid & 15) * 8;
    const int am0 = swzg(cm >> 2), am1 = swzg((cm >> 2) + 1);
    const int bn0 = swzg(cn >> 2), bn1 = swzg((cn >> 2) + 1);

    float acc[8][8];
#pragma unroll
    for (int i = 0; i < 8; ++i)
#pragma unroll
        for (int j = 0; j < 8; ++j) acc[i][j] = 0.0f;

    float4 sa[4], sb[4];
#pragma unroll
    for (int j = 0; j < 4; ++j) { sa[j] = Ag[j]; sb[j] = Bg[j]; }

    for (int kt = 0; kt < KTILES; ++kt) {
        __syncthreads();
#pragma unroll
        for (int j = 0; j < 4; ++j) {
            const int kq = (sc + j) * 4;
            Asm[kq + 0][swr] = sa[j].x;
            Asm[kq + 1][swr] = sa[j].y;
            Asm[kq + 2][swr] = sa[j].z;
            Asm[kq + 3][swr] = sa[j].w;
            Bsm[kq + 0][swr] = sb[j].x;
            Bsm[kq + 1][swr] = sb[j].y;
            Bsm[kq + 2][swr] = sb[j].z;
            Bsm[kq + 3][swr] = sb[j].w;
        }
        __syncthreads();

        if (kt + 1 < KTILES) {
            Ag += KC / 4;
            Bg += KC / 4;
#pragma unroll
            for (int j = 0; j < 4; ++j) { sa[j] = Ag[j]; sb[j] = Bg[j]; }
        }

#pragma unroll 8
        for (int kc = 0; kc < KC; ++kc) {
            const float4* Ar = reinterpret_cast<const float4*>(&Asm[kc][0]);
            const float4* Br = reinterpret_cast<const float4*>(&Bsm[kc][0]);
            float4 a0 = Ar[am0];
            float4 a1 = Ar[am1];
            float4 b0 = Br[bn0];
            float4 b1 = Br[bn1];
            const float av[8] = {a0.x, a0.y, a0.z, a0.w, a1.x, a1.y, a1.z, a1.w};
            const float bv[8] = {b0.x, b0.y, b0.z, b0.w, b1.x, b1.y, b1.z, b1.w};
#pragma unroll
            for (int i = 0; i < 8; ++i)
#pragma unroll
                for (int j = 0; j < 8; ++j)
                    acc[i][j] = fmaf(av[i], bv[j], acc[i][j]);
        }
    }

#pragma unroll
    for (int i = 0; i < 8; ++i) {
        float* zr = z + (size_t)(m0 + cm + i) * HIDDIM + n0 + cn;
        float4 v0 = {acc[i][0], acc[i][1], acc[i][2], acc[i][3]};
        float4 v1 = {acc[i][4], acc[i][5], acc[i][6], acc[i][7]};
        *reinterpret_cast<float4*>(zr)     = v0;
        *reinterpret_cast<float4*>(zr + 4) = v1;
    }
}

// ---------------------------------------------------------------------------
// Kernel 2: membrane scan, producer/consumer wave specialization.
// 256 blocks x 128 threads. Wave 1 = producer: stages chunk c+1 into LDS
// (global->reg->ds_write) while its loads for chunk c+2 are in flight (its
// vmcnt FIFO holds ONLY loads -> compiler's counted waits work). Wave 0 =
// consumer: pure serial membrane scan from LDS + coalesced 256B spike
// stores (its stores never gate anything). One s_barrier per chunk.
// Static even/odd reg sets (ra/rb) -> no runtime-indexed arrays (rule #20).
// ---------------------------------------------------------------------------
#define LWRITE(BUF, R)                                                        \
    _Pragma("unroll")                                                         \
    for (int j = 0; j < 8; ++j)                                               \
        *reinterpret_cast<float4*>(&zl[BUF][j * 4 + tr][hc]) = R[j];

#define GLOAD(R, C)                                                           \
    _Pragma("unroll")                                                         \
    for (int j = 0; j < 8; ++j)                                               \
        R[j] = *reinterpret_cast<const float4*>(                              \
            zbase + (size_t)((C) * ST + j * 4 + tr) * HIDDIM + hc);

#define SCAN_CHUNK(BUF, C)                                                    \
    {                                                                         \
        float* orow = obase + (size_t)(C) * ST * HIDDIM + lane;               \
        _Pragma("unroll 8")                                                   \
        for (int r = 0; r < ST; ++r) {                                        \
            float zv = zl[BUF][r][lane] + bb;                                 \
            mem = fmaf(ALPHA, mem, zv);                                       \
            bool s = (mem >= tt);                                             \
            orow[(size_t)r * HIDDIM] = s ? 1.0f : 0.0f;                       \
            mem = s ? 0.0f : mem;                                             \
        }                                                                     \
    }

#define FENCE_BARRIER()                                                       \
    asm volatile("s_waitcnt lgkmcnt(0)" ::: "memory");                        \
    __builtin_amdgcn_sched_barrier(0);                                        \
    __builtin_amdgcn_s_barrier();

__global__ __launch_bounds__(128)
void snn_scan(const float* __restrict__ zsrc, float* __restrict__ out,
              const float* __restrict__ bias, const float* __restrict__ thr)
{
    __shared__ float zl[2][ST][SH];   // 16 KB

    const int tid  = threadIdx.x;
    const int lane = tid & 63;
    const int wave = tid >> 6;
    const int b    = blockIdx.x >> 3;
    const int h0   = (blockIdx.x & 7) * SH;

    const float* zbase = zsrc + (size_t)b * TSTEPS * HIDDIM + h0;
    float*       obase = out  + (size_t)b * TSTEPS * HIDDIM + h0;

    const int tr = lane >> 4;         // t-row within 4-row group
    const int hc = (lane & 15) * 4;   // h column (float index)

    const float bb = (wave == 0) ? bias[h0 + lane] : 0.0f;
    const float tt = (wave == 0) ? thr[h0 + lane]  : 1.0e30f;
    float mem = 0.0f;

    float4 ra[8], rb[8];

    // prologue: producer stages chunk 0 into buf0, chunk 1 into regs
    if (wave == 1) {
        GLOAD(ra, 0)
        GLOAD(rb, 1)
        __builtin_amdgcn_sched_barrier(0);
        LWRITE(0, ra)
    }
    FENCE_BARRIER();

    for (int cc = 0; cc < SNC / 2; ++cc) {
        const int c = 2 * cc;

        // ---- epoch even: consumer scans chunk c (buf0)
        if (wave == 1) {
            if (c + 2 < SNC) { GLOAD(ra, c + 2) }       // loads in flight
            __builtin_amdgcn_sched_barrier(0);
            LWRITE(1, rb)                                // chunk c+1
        } else {
            SCAN_CHUNK(0, c)
        }
        FENCE_BARRIER();

        // ---- epoch odd: consumer scans chunk c+1 (buf1)
        if (wave == 1) {
            if (c + 3 < SNC) { GLOAD(rb, c + 3) }
            __builtin_amdgcn_sched_barrier(0);
            if (c + 2 < SNC) { LWRITE(0, ra) }           // chunk c+2
        } else {
            SCAN_CHUNK(1, c + 1)
        }
        FENCE_BARRIER();
    }

    if (wave == 0)
        out[(size_t)MTOT * HIDDIM + (size_t)b * HIDDIM + h0 + lane] = mem;
}

extern "C" void kernel_launch(void* const* d_in, const int* in_sizes, int n_in,
                              void* d_out, int out_size, void* d_ws, size_t ws_size,
                              hipStream_t stream)
{
    const float* x    = (const float*)d_in[0];
    const float* W    = (const float*)d_in[1];
    const float* bias = (const float*)d_in[2];
    const float* thr  = (const float*)d_in[3];
    float* out = (float*)d_out;

    (void)in_sizes; (void)n_in; (void)out_size;

    const size_t z_bytes = (size_t)MTOT * HIDDIM * sizeof(float);  // 64 MB
    float* zbuf = (ws_size >= z_bytes) ? (float*)d_ws : out;
    // in-place fallback is safe: scan's loads lead its stores by 2 chunks
    // within a row-disjoint (b, h-tile) strip.

    dim3 ggrid((MTOT / MB) * NBLK);  // 1024 blocks
    hipLaunchKernelGGL(snn_gemm, ggrid, dim3(256), 0, stream, x, W, zbuf);

    dim3 sgrid(BATCH * (HIDDIM / SH));  // 256 blocks x 128 threads
    hipLaunchKernelGGL(snn_scan, sgrid, dim3(128), 0, stream, zbuf, out, bias, thr);
}